// Round 9
// baseline (262.731 us; speedup 1.0000x reference)
//
#include <hip/hip_runtime.h>
#include <math.h>

#define BB 4
#define LL 4096
#define CC 768
#define KHH 7
#define PADK 3
#define ROWS (BB*LL)      // 16384
#define NKP  (BB*KHH*LL)  // 114688
#define GK   (KHH*CC)     // 5376
#define NT   (GK/64)      // 84
#define NKC  (GK/8)       // 672

typedef unsigned short ushort8 __attribute__((ext_vector_type(8)));
typedef short short8 __attribute__((ext_vector_type(8)));
typedef float f32x4 __attribute__((ext_vector_type(4)));

__device__ __forceinline__ float bf2f(unsigned short u) {
    return __uint_as_float(((unsigned)u) << 16);
}
__device__ __forceinline__ unsigned short f2bf(float x) {
    unsigned u = __float_as_uint(x);
    return (unsigned short)((u + 0x7FFFu + ((u >> 16) & 1u)) >> 16);
}

// ---------------- K1: layernorm + gate -> h_bf16 ----------------
__global__ __launch_bounds__(256) void k_ln(const float* __restrict__ x,
        const float* __restrict__ mask, const float* __restrict__ special,
        const float* __restrict__ lnw, const float* __restrict__ lnb,
        unsigned short* __restrict__ hb, float* __restrict__ gate) {
    int row = blockIdx.x;
    const float* xr = x + (size_t)row * CC;
    float s = 0.f, q = 0.f;
    for (int i = threadIdx.x; i < CC; i += 256) { float v = xr[i]; s += v; q += v * v; }
    for (int o = 32; o; o >>= 1) { s += __shfl_xor(s, o); q += __shfl_xor(q, o); }
    __shared__ float ss[4], sq[4];
    int wid = threadIdx.x >> 6;
    if ((threadIdx.x & 63) == 0) { ss[wid] = s; sq[wid] = q; }
    __syncthreads();
    s = ss[0] + ss[1] + ss[2] + ss[3];
    q = sq[0] + sq[1] + sq[2] + sq[3];
    float mu  = s * (1.f / CC);
    float var = fmaxf(q * (1.f / CC) - mu * mu, 0.f);
    float rstd = rsqrtf(var + 1e-12f);
    unsigned short* hr = hb + (size_t)row * CC;
    for (int i = threadIdx.x; i < CC; i += 256)
        hr[i] = f2bf((xr[i] - mu) * rstd * lnw[i] + lnb[i]);
    if (threadIdx.x == 0) gate[row] = (1.f - special[row]) * mask[row];
}

// ---------------- K2: reg_w[o][c][k] -> Wbt[kc][o][e] bf16  (kc = K/8, K = k*768+c) ----------------
__global__ __launch_bounds__(256) void k_wbt(const float* __restrict__ rw,
                                             unsigned short* __restrict__ wbt) {
    __shared__ float s[GK];
    int o = blockIdx.x;
    for (int i = threadIdx.x; i < GK; i += 256) s[i] = rw[(size_t)o * GK + i];
    __syncthreads();
    for (int kc = threadIdx.x; kc < NKC; kc += 256) {
        int k = kc / 96;               // tap
        int c0 = (kc - k * 96) * 8;    // channel base
        ushort8 r;
#pragma unroll
        for (int e = 0; e < 8; ++e) r[e] = f2bf(s[(c0 + e) * KHH + k]);
        *(ushort8*)(wbt + ((size_t)kc * CC + o) * 8) = r;
    }
}

// ---------------- K2b: conv weights -> wcb[i][c] bf16 ----------------
__global__ __launch_bounds__(256) void k_wcb(const float* __restrict__ ow, const float* __restrict__ mw,
                                             unsigned short* __restrict__ wcb) {
    int i = blockIdx.x;
    for (int c = threadIdx.x; c < CC; c += 256) {
        float v = 0.f;
        if (i < 49)      v = ow[(size_t)(i / 7) * (CC * KHH) + (size_t)c * KHH + (i % 7)];
        else if (i < 98) { int j = i - 49; v = mw[(size_t)(j / 7) * (CC * KHH) + (size_t)c * KHH + (j % 7)]; }
        wcb[(size_t)i * CC + c] = f2bf(v);
    }
}

// ---------------- K3: d[row][i] = sum_c hb[row][c] * wcb[i][c] ----------------
__global__ __launch_bounds__(256) void k_dg2(const unsigned short* __restrict__ A,
        const unsigned short* __restrict__ Bm, float* __restrict__ d) {
    __shared__ __align__(16) char As[128 * 128];
    __shared__ __align__(16) char Bs[128 * 128];
    int r0 = blockIdx.x * 128;
    int t = threadIdx.x;
    int lane = t & 63, w = t >> 6;
    int wr = w >> 1, wc = w & 1;
    f32x4 acc[4][4];
#pragma unroll
    for (int m = 0; m < 4; ++m)
#pragma unroll
        for (int n = 0; n < 4; ++n) acc[m][n] = (f32x4){0.f, 0.f, 0.f, 0.f};
    int lr = lane & 15;
    int lkb0 = (lane >> 4) * 16;
    for (int kk = 0; kk < CC; kk += 64) {
#pragma unroll
        for (int s = 0; s < 4; ++s) {
            int byteoff = (s * 256 + t) * 16;
            int row = byteoff >> 7;
            int colb = byteoff & 127;
            int sw = (row * 128 + colb) ^ ((row & 7) << 4);
            *(ushort8*)(As + sw) = *(const ushort8*)(A + (size_t)(r0 + row) * CC + kk + (colb >> 1));
            *(ushort8*)(Bs + sw) = *(const ushort8*)(Bm + (size_t)row * CC + kk + (colb >> 1));
        }
        __syncthreads();
#pragma unroll
        for (int ks = 0; ks < 2; ++ks) {
            short8 av[4], bv[4];
            int lkb = lkb0 + ks * 64;
#pragma unroll
            for (int m = 0; m < 4; ++m) {
                int ar = wr * 64 + m * 16 + lr;
                av[m] = *(const short8*)(As + ((ar * 128 + lkb) ^ ((ar & 7) << 4)));
            }
#pragma unroll
            for (int n = 0; n < 4; ++n) {
                int br = wc * 64 + n * 16 + lr;
                bv[n] = *(const short8*)(Bs + ((br * 128 + lkb) ^ ((br & 7) << 4)));
            }
#pragma unroll
            for (int m = 0; m < 4; ++m)
#pragma unroll
                for (int n = 0; n < 4; ++n)
                    acc[m][n] = __builtin_amdgcn_mfma_f32_16x16x32_bf16(av[m], bv[n], acc[m][n], 0, 0, 0);
        }
        __syncthreads();
    }
    int lr4 = (lane >> 4) * 4, lc = lane & 15;
#pragma unroll
    for (int m = 0; m < 4; ++m) {
        int gr = r0 + wr * 64 + m * 16 + lr4;
#pragma unroll
        for (int n = 0; n < 4; ++n) {
            int gc = wc * 64 + n * 16 + lc;
#pragma unroll
            for (int j = 0; j < 4; ++j)
                d[(size_t)(gr + j) * 128 + gc] = acc[m][n][j];
        }
    }
}

// ---------------- K4: sampling params ----------------
__global__ __launch_bounds__(256) void k_off(const float* __restrict__ d,
        const float* __restrict__ offb, const float* __restrict__ modb,
        const float* __restrict__ gate,
        int* __restrict__ idx0, int* __restrict__ idx1,
        float* __restrict__ w0a, float* __restrict__ w1a) {
    int flat = blockIdx.x * 256 + threadIdx.x;   // b*7*L + k*L + p
    if (flat >= NKP) return;
    int p = flat & (LL - 1);
    int k = (flat >> 12) % KHH;
    int b = flat / (KHH * LL);
    float offa = offb[k], moda = modb[k];
#pragma unroll
    for (int j = 0; j < KHH; ++j) {
        int q = p + j - PADK;
        if (q >= 0 && q < LL) {
            const float* dr = d + (size_t)(b * LL + q) * 128;
            offa += dr[k * 7 + j];
            moda += dr[49 + k * 7 + j];
        }
    }
    float modv = 2.f / (1.f + expf(-moda));
    float pos = (float)(p - PADK + k) + offa;
    pos = fminf(fmaxf(pos, -1.0e9f), 1.0e9f);
    float f = floorf(pos);
    float tf = pos - f;
    int i0 = (int)f;
    int i1 = i0 + 1;
    float in0 = (i0 >= 0 && i0 < LL) ? 1.f : 0.f;
    float in1 = (i1 >= 0 && i1 < LL) ? 1.f : 0.f;
    int c0 = min(max(i0, 0), LL - 1);
    int c1 = min(max(i1, 0), LL - 1);
    float g0 = gate[b * LL + c0] * in0;
    float g1 = gate[b * LL + c1] * in1;
    w0a[flat] = modv * (1.f - tf) * g0;
    w1a[flat] = modv * tf * g1;
    idx0[flat] = c0;
    idx1[flat] = c1;
}

// ---------------- K5: fused sample+GEMM; depth-2 A pipeline, raw barrier (counted vmcnt) ----------------
// BM=128, BN=384, BK=64; 512 threads = 8 waves (2x4), wave tile 64x96 = 4x6 frags 16x16x32

#define STEPOFF 49152   // 8 kc per step * 768 * 8 elems
#define KSOFF   24576   // 4 kc * 768 * 8 elems

#define LOADB(Q, KS, D0, D1, D2, D3, D4, D5) do { \
    const unsigned short* _q = (Q) + (KS) * KSOFF; \
    D0 = *(const short8*)(_q); \
    D1 = *(const short8*)(_q + 128); \
    D2 = *(const short8*)(_q + 256); \
    D3 = *(const short8*)(_q + 384); \
    D4 = *(const short8*)(_q + 512); \
    D5 = *(const short8*)(_q + 640); \
} while (0)

#define MFMA_ROW(AV, M, B0, B1, B2, B3, B4, B5) \
    acc[M][0] = __builtin_amdgcn_mfma_f32_16x16x32_bf16(AV, B0, acc[M][0], 0, 0, 0); \
    acc[M][1] = __builtin_amdgcn_mfma_f32_16x16x32_bf16(AV, B1, acc[M][1], 0, 0, 0); \
    acc[M][2] = __builtin_amdgcn_mfma_f32_16x16x32_bf16(AV, B2, acc[M][2], 0, 0, 0); \
    acc[M][3] = __builtin_amdgcn_mfma_f32_16x16x32_bf16(AV, B3, acc[M][3], 0, 0, 0); \
    acc[M][4] = __builtin_amdgcn_mfma_f32_16x16x32_bf16(AV, B4, acc[M][4], 0, 0, 0); \
    acc[M][5] = __builtin_amdgcn_mfma_f32_16x16x32_bf16(AV, B5, acc[M][5], 0, 0, 0);

#define COMPUTE_KS(ASB, KS, B0, B1, B2, B3, B4, B5) do { \
    __builtin_amdgcn_s_setprio(1); \
    int _lkb = ke0 * 2 + (KS) * 64; \
    short8 _av0, _av1, _av2, _av3; \
    { int ar = wr * 64 + 0 * 16 + lr; _av0 = *(const short8*)((ASB) + ar * 128 + (_lkb ^ ((ar & 7) << 4))); } \
    { int ar = wr * 64 + 1 * 16 + lr; _av1 = *(const short8*)((ASB) + ar * 128 + (_lkb ^ ((ar & 7) << 4))); } \
    { int ar = wr * 64 + 2 * 16 + lr; _av2 = *(const short8*)((ASB) + ar * 128 + (_lkb ^ ((ar & 7) << 4))); } \
    { int ar = wr * 64 + 3 * 16 + lr; _av3 = *(const short8*)((ASB) + ar * 128 + (_lkb ^ ((ar & 7) << 4))); } \
    MFMA_ROW(_av0, 0, B0, B1, B2, B3, B4, B5) \
    MFMA_ROW(_av1, 1, B0, B1, B2, B3, B4, B5) \
    MFMA_ROW(_av2, 2, B0, B1, B2, B3, B4, B5) \
    MFMA_ROW(_av3, 3, B0, B1, B2, B3, B4, B5) \
    __builtin_amdgcn_s_setprio(0); \
} while (0)

// raw barrier: LDS drained, global loads stay in flight (T4)
#define BAR() do { \
    asm volatile("s_waitcnt lgkmcnt(0)" ::: "memory"); \
    __builtin_amdgcn_s_barrier(); \
    __builtin_amdgcn_sched_barrier(0); \
} while (0)

__global__ __launch_bounds__(512, 2) void k_fgemm(const unsigned short* __restrict__ hb,
        const unsigned short* __restrict__ Wbt,
        const int* __restrict__ idx0, const int* __restrict__ idx1,
        const float* __restrict__ w0a, const float* __restrict__ w1a,
        const float* __restrict__ resid, float* __restrict__ out) {
    __shared__ __align__(16) char As[2][128 * 128];

    int bid = blockIdx.x;
    int nhalf = (bid & 7) >> 2;                 // XCDs 0-3 -> half 0, 4-7 -> half 1
    int rowtile = (bid >> 3) * 4 + (bid & 3);   // bijective 0..127
    int r0 = rowtile * 128;
    int o0 = nhalf * 384;
    int b = r0 >> 12;
    int p0 = r0 & (LL - 1);
    int pbase = ((b * KHH) << 12) + p0;
    const unsigned short* hbB = hb + (size_t)b * LL * CC;

    int t = threadIdx.x;
    int lane = t & 63, w = t >> 6;
    int wr = w >> 2, wc = w & 3;
    int lr = lane & 15;
    int ke0 = (lane >> 4) * 8;     // elem offset of lane's 8-elem k-chunk

    // per-lane B base pointer into Wbt; advances STEPOFF per step
    const unsigned short* pB = Wbt + ((size_t)(lane >> 4) * CC + o0 + wc * 96 + lr) * 8;

    // A-build mapping: row = t>>2 (0..127), seg = t&3 (16 elems each)
    int arow = t >> 2, aseg = t & 3;
    int acolb = aseg * 32;
    int aswz0 = arow * 128 + (acolb ^ ((arow & 7) << 4));
    int aswz1 = arow * 128 + ((acolb + 16) ^ ((arow & 7) << 4));

    f32x4 acc[4][6];
#pragma unroll
    for (int m = 0; m < 4; ++m)
#pragma unroll
        for (int n = 0; n < 6; ++n) acc[m][n] = (f32x4){0.f, 0.f, 0.f, 0.f};

    // per-set A-pipeline state (set0 = even steps, set1 = odd steps)
    int tap0 = 0, c00 = 0, g0_0 = 0, g1_0 = 0;
    float wa0 = 0.f, wb0 = 0.f;
    ushort8 la0_0, la1_0, la2_0, la3_0;
    int tap1 = 0, c01 = 0, g0_1 = 0, g1_1 = 0;
    float wa1 = 0.f, wb1 = 0.f;
    ushort8 la0_1, la1_1, la2_1, la3_1;

    // B staging (named sets, round-7 rotation)
    short8 S0_0, S0_1, S0_2, S0_3, S0_4, S0_5;   // ks0 even
    short8 S1_0, S1_1, S1_2, S1_3, S1_4, S1_5;   // ks1 (reloaded late each step)
    short8 S2_0, S2_1, S2_2, S2_3, S2_4, S2_5;   // ks0 odd

    auto loadIdx0 = [&]() {
        int pf = pbase + (tap0 << 12) + arow;
        g0_0 = idx0[pf]; g1_0 = idx1[pf]; wa0 = w0a[pf]; wb0 = w1a[pf];
    };
    auto loadIdx1 = [&]() {
        int pf = pbase + (tap1 << 12) + arow;
        g0_1 = idx0[pf]; g1_1 = idx1[pf]; wa1 = w0a[pf]; wb1 = w1a[pf];
    };
    auto gatherRaw0 = [&]() {
        const unsigned short* s0 = hbB + (size_t)g0_0 * CC + c00 + aseg * 16;
        const unsigned short* s1 = hbB + (size_t)g1_0 * CC + c00 + aseg * 16;
        la0_0 = *(const ushort8*)(s0);
        la1_0 = *(const ushort8*)(s0 + 8);
        la2_0 = *(const ushort8*)(s1);
        la3_0 = *(const ushort8*)(s1 + 8);
    };
    auto gatherRaw1 = [&]() {
        const unsigned short* s0 = hbB + (size_t)g0_1 * CC + c01 + aseg * 16;
        const unsigned short* s1 = hbB + (size_t)g1_1 * CC + c01 + aseg * 16;
        la0_1 = *(const ushort8*)(s0);
        la1_1 = *(const ushort8*)(s0 + 8);
        la2_1 = *(const ushort8*)(s1);
        la3_1 = *(const ushort8*)(s1 + 8);
    };
    auto gatherAdv0 = [&]() {   // advance set0 by 2 steps (+128 cols) and gather
        c00 += 128;
        if (c00 >= CC) { c00 -= CC; ++tap0; loadIdx0(); }
        gatherRaw0();
    };
    auto gatherAdv1 = [&]() {
        c01 += 128;
        if (c01 >= CC) { c01 -= CC; ++tap1; loadIdx1(); }
        gatherRaw1();
    };
    auto writeA0 = [&](char* Asb) {
        ushort8 ra, rb;
#pragma unroll
        for (int e = 0; e < 8; ++e) ra[e] = f2bf(fmaf(wa0, bf2f(la0_0[e]), wb0 * bf2f(la2_0[e])));
#pragma unroll
        for (int e = 0; e < 8; ++e) rb[e] = f2bf(fmaf(wa0, bf2f(la1_0[e]), wb0 * bf2f(la3_0[e])));
        *(ushort8*)(Asb + aswz0) = ra;
        *(ushort8*)(Asb + aswz1) = rb;
    };
    auto writeA1 = [&](char* Asb) {
        ushort8 ra, rb;
#pragma unroll
        for (int e = 0; e < 8; ++e) ra[e] = f2bf(fmaf(wa1, bf2f(la0_1[e]), wb1 * bf2f(la2_1[e])));
#pragma unroll
        for (int e = 0; e < 8; ++e) rb[e] = f2bf(fmaf(wa1, bf2f(la1_1[e]), wb1 * bf2f(la3_1[e])));
        *(ushort8*)(Asb + aswz0) = ra;
        *(ushort8*)(Asb + aswz1) = rb;
    };

    // ---- prologue: G_0, G_1, B(step0); W_0 ----
    tap0 = 0; c00 = 0; loadIdx0(); gatherRaw0();     // G_0 -> set0
    tap1 = 0; c01 = 64; loadIdx1(); gatherRaw1();    // G_1 -> set1
    LOADB(pB, 0, S0_0, S0_1, S0_2, S0_3, S0_4, S0_5);
    LOADB(pB, 1, S1_0, S1_1, S1_2, S1_3, S1_4, S1_5);
    writeA0(As[0]);                                   // W_0
    BAR();

    for (int sp = 0; sp < NT; sp += 2) {
        // ---------------- even step s = sp ----------------
        {
            bool gmore = (sp + 2 < NT);
            const unsigned short* pN = pB + STEPOFF;
            writeA1(As[1]);                              // W_{sp+1} (gathered 1 step ago)
            __builtin_amdgcn_sched_barrier(0);
            if (gmore) gatherAdv0();                     // G_{sp+2} -> set0
            LOADB(pN, 0, S2_0, S2_1, S2_2, S2_3, S2_4, S2_5);   // B ks0 for sp+1
            COMPUTE_KS(As[0], 0, S0_0, S0_1, S0_2, S0_3, S0_4, S0_5);
            COMPUTE_KS(As[0], 1, S1_0, S1_1, S1_2, S1_3, S1_4, S1_5);
            LOADB(pN, 1, S1_0, S1_1, S1_2, S1_3, S1_4, S1_5);   // B ks1 for sp+1
            BAR();
        }
        // ---------------- odd step s = sp+1 ----------------
        {
            bool wmore = (sp + 2 < NT);
            bool gmore = (sp + 3 < NT);
            const unsigned short* pN2 = pB + 2 * STEPOFF;
            if (wmore) writeA0(As[0]);                   // W_{sp+2}
            __builtin_amdgcn_sched_barrier(0);
            if (gmore) gatherAdv1();                     // G_{sp+3} -> set1
            if (wmore) LOADB(pN2, 0, S0_0, S0_1, S0_2, S0_3, S0_4, S0_5);  // B ks0 for sp+2
            COMPUTE_KS(As[1], 0, S2_0, S2_1, S2_2, S2_3, S2_4, S2_5);
            COMPUTE_KS(As[1], 1, S1_0, S1_1, S1_2, S1_3, S1_4, S1_5);
            if (wmore) LOADB(pN2, 1, S1_0, S1_1, S1_2, S1_3, S1_4, S1_5);  // B ks1 for sp+2
            BAR();
            pB = pN2;
        }
    }

    // epilogue: + residual
    int lr4 = (lane >> 4) * 4, lc = lane & 15;
#pragma unroll
    for (int m = 0; m < 4; ++m) {
        int gr = r0 + wr * 64 + m * 16 + lr4;
#pragma unroll
        for (int n = 0; n < 6; ++n) {
            int gc = o0 + wc * 96 + n * 16 + lc;
#pragma unroll
            for (int j = 0; j < 4; ++j) {
                size_t idx = (size_t)(gr + j) * CC + gc;
                out[idx] = acc[m][n][j] + resid[idx];
            }
        }
    }
}

extern "C" void kernel_launch(void* const* d_in, const int* in_sizes, int n_in,
                              void* d_out, int out_size, void* d_ws, size_t ws_size,
                              hipStream_t stream) {
    const float* x   = (const float*)d_in[0];
    const float* am  = (const float*)d_in[1];
    const float* stm = (const float*)d_in[2];
    const float* lnw = (const float*)d_in[3];
    const float* lnb = (const float*)d_in[4];
    const float* ow  = (const float*)d_in[5];
    const float* ob  = (const float*)d_in[6];
    const float* mw  = (const float*)d_in[7];
    const float* mb  = (const float*)d_in[8];
    const float* rw  = (const float*)d_in[9];
    float* out = (float*)d_out;

    char* ws = (char*)d_ws;
    size_t off = 0;
    auto carve = [&](size_t bytes) -> char* {
        char* p = ws + off;
        off += (bytes + 255) & ~(size_t)255;
        return p;
    };
    unsigned short* hb  = (unsigned short*)carve((size_t)ROWS * CC * 2);   // 25.2 MB
    unsigned short* wbt = (unsigned short*)carve((size_t)NKC * CC * 8 * 2);// 8.25 MB
    unsigned short* wcb = (unsigned short*)carve((size_t)128 * CC * 2);    // 0.20 MB
    float* d    = (float*)carve((size_t)ROWS * 128 * 4);                   // 8.4 MB
    float* gate = (float*)carve((size_t)ROWS * 4);
    int*   i0   = (int*)carve((size_t)NKP * 4);
    int*   i1   = (int*)carve((size_t)NKP * 4);
    float* w0   = (float*)carve((size_t)NKP * 4);
    float* w1   = (float*)carve((size_t)NKP * 4);

    k_ln<<<ROWS, 256, 0, stream>>>(x, am, stm, lnw, lnb, hb, gate);
    k_wbt<<<CC, 256, 0, stream>>>(rw, wbt);
    k_wcb<<<128, 256, 0, stream>>>(ow, mw, wcb);
    k_dg2<<<ROWS / 128, 256, 0, stream>>>(hb, wcb, d);
    k_off<<<NKP / 256, 256, 0, stream>>>(d, ob, mb, gate, i0, i1, w0, w1);
    k_fgemm<<<256, 512, 0, stream>>>(hb, wbt, i0, i1, w0, w1, x, out);
}

// Round 10
// 206.647 us; speedup vs baseline: 1.2714x; 1.2714x over previous
//
#include <hip/hip_runtime.h>
#include <math.h>

#define BB 4
#define LL 4096
#define CC 768
#define KHH 7
#define PADK 3
#define ROWS (BB*LL)      // 16384
#define NKP  (BB*KHH*LL)  // 114688
#define GK   (KHH*CC)     // 5376
#define NT   (GK/64)      // 84
#define NKC  (GK/8)       // 672

typedef unsigned short ushort8 __attribute__((ext_vector_type(8)));
typedef short short8 __attribute__((ext_vector_type(8)));
typedef float f32x4 __attribute__((ext_vector_type(4)));

__device__ __forceinline__ float bf2f(unsigned short u) {
    return __uint_as_float(((unsigned)u) << 16);
}
__device__ __forceinline__ unsigned short f2bf(float x) {
    unsigned u = __float_as_uint(x);
    return (unsigned short)((u + 0x7FFFu + ((u >> 16) & 1u)) >> 16);
}

// ---------------- K1: layernorm + gate -> h_bf16 ----------------
__global__ __launch_bounds__(256) void k_ln(const float* __restrict__ x,
        const float* __restrict__ mask, const float* __restrict__ special,
        const float* __restrict__ lnw, const float* __restrict__ lnb,
        unsigned short* __restrict__ hb, float* __restrict__ gate) {
    int row = blockIdx.x;
    const float* xr = x + (size_t)row * CC;
    float s = 0.f, q = 0.f;
    for (int i = threadIdx.x; i < CC; i += 256) { float v = xr[i]; s += v; q += v * v; }
    for (int o = 32; o; o >>= 1) { s += __shfl_xor(s, o); q += __shfl_xor(q, o); }
    __shared__ float ss[4], sq[4];
    int wid = threadIdx.x >> 6;
    if ((threadIdx.x & 63) == 0) { ss[wid] = s; sq[wid] = q; }
    __syncthreads();
    s = ss[0] + ss[1] + ss[2] + ss[3];
    q = sq[0] + sq[1] + sq[2] + sq[3];
    float mu  = s * (1.f / CC);
    float var = fmaxf(q * (1.f / CC) - mu * mu, 0.f);
    float rstd = rsqrtf(var + 1e-12f);
    unsigned short* hr = hb + (size_t)row * CC;
    for (int i = threadIdx.x; i < CC; i += 256)
        hr[i] = f2bf((xr[i] - mu) * rstd * lnw[i] + lnb[i]);
    if (threadIdx.x == 0) gate[row] = (1.f - special[row]) * mask[row];
}

// ---------------- K2: reg_w[o][c][k] -> Wbt[kc][o][e] bf16  (kc = K/8, K = k*768+c) ----------------
__global__ __launch_bounds__(256) void k_wbt(const float* __restrict__ rw,
                                             unsigned short* __restrict__ wbt) {
    __shared__ float s[GK];
    int o = blockIdx.x;
    for (int i = threadIdx.x; i < GK; i += 256) s[i] = rw[(size_t)o * GK + i];
    __syncthreads();
    for (int kc = threadIdx.x; kc < NKC; kc += 256) {
        int k = kc / 96;               // tap
        int c0 = (kc - k * 96) * 8;    // channel base
        ushort8 r;
#pragma unroll
        for (int e = 0; e < 8; ++e) r[e] = f2bf(s[(c0 + e) * KHH + k]);
        *(ushort8*)(wbt + ((size_t)kc * CC + o) * 8) = r;
    }
}

// ---------------- K2b: conv weights -> wcb[i][c] bf16 ----------------
__global__ __launch_bounds__(256) void k_wcb(const float* __restrict__ ow, const float* __restrict__ mw,
                                             unsigned short* __restrict__ wcb) {
    int i = blockIdx.x;
    for (int c = threadIdx.x; c < CC; c += 256) {
        float v = 0.f;
        if (i < 49)      v = ow[(size_t)(i / 7) * (CC * KHH) + (size_t)c * KHH + (i % 7)];
        else if (i < 98) { int j = i - 49; v = mw[(size_t)(j / 7) * (CC * KHH) + (size_t)c * KHH + (j % 7)]; }
        wcb[(size_t)i * CC + c] = f2bf(v);
    }
}

// ---------------- K3: d[row][i] = sum_c hb[row][c] * wcb[i][c] ----------------
__global__ __launch_bounds__(256) void k_dg2(const unsigned short* __restrict__ A,
        const unsigned short* __restrict__ Bm, float* __restrict__ d) {
    __shared__ __align__(16) char As[128 * 128];
    __shared__ __align__(16) char Bs[128 * 128];
    int r0 = blockIdx.x * 128;
    int t = threadIdx.x;
    int lane = t & 63, w = t >> 6;
    int wr = w >> 1, wc = w & 1;
    f32x4 acc[4][4];
#pragma unroll
    for (int m = 0; m < 4; ++m)
#pragma unroll
        for (int n = 0; n < 4; ++n) acc[m][n] = (f32x4){0.f, 0.f, 0.f, 0.f};
    int lr = lane & 15;
    int lkb0 = (lane >> 4) * 16;
    for (int kk = 0; kk < CC; kk += 64) {
#pragma unroll
        for (int s = 0; s < 4; ++s) {
            int byteoff = (s * 256 + t) * 16;
            int row = byteoff >> 7;
            int colb = byteoff & 127;
            int sw = (row * 128 + colb) ^ ((row & 7) << 4);
            *(ushort8*)(As + sw) = *(const ushort8*)(A + (size_t)(r0 + row) * CC + kk + (colb >> 1));
            *(ushort8*)(Bs + sw) = *(const ushort8*)(Bm + (size_t)row * CC + kk + (colb >> 1));
        }
        __syncthreads();
#pragma unroll
        for (int ks = 0; ks < 2; ++ks) {
            short8 av[4], bv[4];
            int lkb = lkb0 + ks * 64;
#pragma unroll
            for (int m = 0; m < 4; ++m) {
                int ar = wr * 64 + m * 16 + lr;
                av[m] = *(const short8*)(As + ((ar * 128 + lkb) ^ ((ar & 7) << 4)));
            }
#pragma unroll
            for (int n = 0; n < 4; ++n) {
                int br = wc * 64 + n * 16 + lr;
                bv[n] = *(const short8*)(Bs + ((br * 128 + lkb) ^ ((br & 7) << 4)));
            }
#pragma unroll
            for (int m = 0; m < 4; ++m)
#pragma unroll
                for (int n = 0; n < 4; ++n)
                    acc[m][n] = __builtin_amdgcn_mfma_f32_16x16x32_bf16(av[m], bv[n], acc[m][n], 0, 0, 0);
        }
        __syncthreads();
    }
    int lr4 = (lane >> 4) * 4, lc = lane & 15;
#pragma unroll
    for (int m = 0; m < 4; ++m) {
        int gr = r0 + wr * 64 + m * 16 + lr4;
#pragma unroll
        for (int n = 0; n < 4; ++n) {
            int gc = wc * 64 + n * 16 + lc;
#pragma unroll
            for (int j = 0; j < 4; ++j)
                d[(size_t)(gr + j) * 128 + gc] = acc[m][n][j];
        }
    }
}

// ---------------- K4: sampling params ----------------
__global__ __launch_bounds__(256) void k_off(const float* __restrict__ d,
        const float* __restrict__ offb, const float* __restrict__ modb,
        const float* __restrict__ gate,
        int* __restrict__ idx0, int* __restrict__ idx1,
        float* __restrict__ w0a, float* __restrict__ w1a) {
    int flat = blockIdx.x * 256 + threadIdx.x;   // b*7*L + k*L + p
    if (flat >= NKP) return;
    int p = flat & (LL - 1);
    int k = (flat >> 12) % KHH;
    int b = flat / (KHH * LL);
    float offa = offb[k], moda = modb[k];
#pragma unroll
    for (int j = 0; j < KHH; ++j) {
        int q = p + j - PADK;
        if (q >= 0 && q < LL) {
            const float* dr = d + (size_t)(b * LL + q) * 128;
            offa += dr[k * 7 + j];
            moda += dr[49 + k * 7 + j];
        }
    }
    float modv = 2.f / (1.f + expf(-moda));
    float pos = (float)(p - PADK + k) + offa;
    pos = fminf(fmaxf(pos, -1.0e9f), 1.0e9f);
    float f = floorf(pos);
    float tf = pos - f;
    int i0 = (int)f;
    int i1 = i0 + 1;
    float in0 = (i0 >= 0 && i0 < LL) ? 1.f : 0.f;
    float in1 = (i1 >= 0 && i1 < LL) ? 1.f : 0.f;
    int c0 = min(max(i0, 0), LL - 1);
    int c1 = min(max(i1, 0), LL - 1);
    float g0 = gate[b * LL + c0] * in0;
    float g1 = gate[b * LL + c1] * in1;
    w0a[flat] = modv * (1.f - tf) * g0;
    w1a[flat] = modv * tf * g1;
    idx0[flat] = c0;
    idx1[flat] = c1;
}

// ---------------- K5: fused sample+GEMM; BM=64, 4 waves, 2 independent blocks/CU ----------------
// BM=64, BN=384, BK=64; 256 threads = 4 waves (1x4), wave tile 64x96 = 4x6 frags 16x16x32
// Same per-CU pipe demands as round 7, but two independent barrier domains per CU.

#define STEPOFF 49152   // 8 kc per step * 768 * 8 elems
#define KSOFF   24576   // 4 kc * 768 * 8 elems

#define LOADB(Q, KS, D0, D1, D2, D3, D4, D5) do { \
    const unsigned short* _q = (Q) + (KS) * KSOFF; \
    D0 = *(const short8*)(_q); \
    D1 = *(const short8*)(_q + 128); \
    D2 = *(const short8*)(_q + 256); \
    D3 = *(const short8*)(_q + 384); \
    D4 = *(const short8*)(_q + 512); \
    D5 = *(const short8*)(_q + 640); \
} while (0)

#define MFMA_ROW(AV, M, B0, B1, B2, B3, B4, B5) \
    acc[M][0] = __builtin_amdgcn_mfma_f32_16x16x32_bf16(AV, B0, acc[M][0], 0, 0, 0); \
    acc[M][1] = __builtin_amdgcn_mfma_f32_16x16x32_bf16(AV, B1, acc[M][1], 0, 0, 0); \
    acc[M][2] = __builtin_amdgcn_mfma_f32_16x16x32_bf16(AV, B2, acc[M][2], 0, 0, 0); \
    acc[M][3] = __builtin_amdgcn_mfma_f32_16x16x32_bf16(AV, B3, acc[M][3], 0, 0, 0); \
    acc[M][4] = __builtin_amdgcn_mfma_f32_16x16x32_bf16(AV, B4, acc[M][4], 0, 0, 0); \
    acc[M][5] = __builtin_amdgcn_mfma_f32_16x16x32_bf16(AV, B5, acc[M][5], 0, 0, 0);

#define COMPUTE_KS(ASB, KS, B0, B1, B2, B3, B4, B5) do { \
    __builtin_amdgcn_s_setprio(1); \
    int _lkb = ke0 * 2 + (KS) * 64; \
    short8 _av0, _av1, _av2, _av3; \
    { int ar = 0 * 16 + lr; _av0 = *(const short8*)((ASB) + ar * 128 + (_lkb ^ ((ar & 7) << 4))); } \
    { int ar = 1 * 16 + lr; _av1 = *(const short8*)((ASB) + ar * 128 + (_lkb ^ ((ar & 7) << 4))); } \
    { int ar = 2 * 16 + lr; _av2 = *(const short8*)((ASB) + ar * 128 + (_lkb ^ ((ar & 7) << 4))); } \
    { int ar = 3 * 16 + lr; _av3 = *(const short8*)((ASB) + ar * 128 + (_lkb ^ ((ar & 7) << 4))); } \
    MFMA_ROW(_av0, 0, B0, B1, B2, B3, B4, B5) \
    MFMA_ROW(_av1, 1, B0, B1, B2, B3, B4, B5) \
    MFMA_ROW(_av2, 2, B0, B1, B2, B3, B4, B5) \
    MFMA_ROW(_av3, 3, B0, B1, B2, B3, B4, B5) \
    __builtin_amdgcn_s_setprio(0); \
} while (0)

__global__ __launch_bounds__(256, 2) void k_fgemm(const unsigned short* __restrict__ hb,
        const unsigned short* __restrict__ Wbt,
        const int* __restrict__ idx0, const int* __restrict__ idx1,
        const float* __restrict__ w0a, const float* __restrict__ w1a,
        const float* __restrict__ resid, float* __restrict__ out) {
    __shared__ __align__(16) char As[2][64 * 128];

    int bid = blockIdx.x;
    int nhalf = (bid & 7) >> 2;                 // XCDs 0-3 -> half 0, 4-7 -> half 1
    int rowtile = (bid >> 3) * 4 + (bid & 3);   // bijective 0..255
    int r0 = rowtile * 64;
    int o0 = nhalf * 384;
    int b = r0 >> 12;
    int p0 = r0 & (LL - 1);
    int pbase = ((b * KHH) << 12) + p0;
    const unsigned short* hbB = hb + (size_t)b * LL * CC;

    int t = threadIdx.x;
    int lane = t & 63, wc = t >> 6;             // wave 0..3 owns 96-col strip
    int lr = lane & 15;
    int ke0 = (lane >> 4) * 8;     // elem offset of lane's 8-elem k-chunk

    // per-lane B base pointer into Wbt; advances STEPOFF per step
    const unsigned short* pB = Wbt + ((size_t)(lane >> 4) * CC + o0 + wc * 96 + lr) * 8;

    // A-build mapping: row = t>>2 (0..63), seg = t&3 (16 elems each)
    int arow = t >> 2, aseg = t & 3;
    int acolb = aseg * 32;
    int aswz0 = arow * 128 + (acolb ^ ((arow & 7) << 4));
    int aswz1 = arow * 128 + ((acolb + 16) ^ ((arow & 7) << 4));

    f32x4 acc[4][6];
#pragma unroll
    for (int m = 0; m < 4; ++m)
#pragma unroll
        for (int n = 0; n < 6; ++n) acc[m][n] = (f32x4){0.f, 0.f, 0.f, 0.f};

    // per-tap sampling regs
    int g0 = 0, g1 = 0;
    float wa = 0.f, wbv = 0.f;
    int cur_tap = -1;

    // staging registers (all individually named)
    ushort8 la0, la1, la2, la3;
    short8 S0_0, S0_1, S0_2, S0_3, S0_4, S0_5;   // ks0 buffer (even steps)
    short8 S1_0, S1_1, S1_2, S1_3, S1_4, S1_5;   // ks1 buffer (reloaded late every step)
    short8 S2_0, S2_1, S2_2, S2_3, S2_4, S2_5;   // ks0 buffer (odd steps)

    auto loadA = [&](int tap, int c0) {
        if (tap != cur_tap) {
            int pf = pbase + (tap << 12) + arow;
            g0 = idx0[pf]; g1 = idx1[pf];
            wa = w0a[pf];  wbv = w1a[pf];
            cur_tap = tap;
        }
        const unsigned short* s0 = hbB + (size_t)g0 * CC + c0 + aseg * 16;
        const unsigned short* s1 = hbB + (size_t)g1 * CC + c0 + aseg * 16;
        la0 = *(const ushort8*)(s0);
        la1 = *(const ushort8*)(s0 + 8);
        la2 = *(const ushort8*)(s1);
        la3 = *(const ushort8*)(s1 + 8);
    };

    auto writeA = [&](char* Asb) {
        ushort8 ra, rb;
#pragma unroll
        for (int e = 0; e < 8; ++e) ra[e] = f2bf(fmaf(wa, bf2f(la0[e]), wbv * bf2f(la2[e])));
#pragma unroll
        for (int e = 0; e < 8; ++e) rb[e] = f2bf(fmaf(wa, bf2f(la1[e]), wbv * bf2f(la3[e])));
        *(ushort8*)(Asb + aswz0) = ra;
        *(ushort8*)(Asb + aswz1) = rb;
    };

    // prologue: step 0 fully staged
    loadA(0, 0);
    LOADB(pB, 0, S0_0, S0_1, S0_2, S0_3, S0_4, S0_5);
    LOADB(pB, 1, S1_0, S1_1, S1_2, S1_3, S1_4, S1_5);
    writeA(As[0]);
    __syncthreads();

    int tap_c = 0, c0_c = 0;
    for (int sp = 0; sp < NT; sp += 2) {
        // ---------------- even step s = sp (computes As[0], S0/S1) ----------------
        {
            int tap_n = tap_c, c0_n = c0_c + 64;
            if (c0_n == CC) { c0_n = 0; ++tap_n; }
            bool more = (sp + 1 < NT);
            const unsigned short* pN = pB + STEPOFF;
            if (more) {
                LOADB(pN, 0, S2_0, S2_1, S2_2, S2_3, S2_4, S2_5);
                loadA(tap_n, c0_n);
            }
            __builtin_amdgcn_sched_barrier(0);
            COMPUTE_KS(As[0], 0, S0_0, S0_1, S0_2, S0_3, S0_4, S0_5);
            COMPUTE_KS(As[0], 1, S1_0, S1_1, S1_2, S1_3, S1_4, S1_5);
            __builtin_amdgcn_sched_barrier(0);
            if (more) {
                LOADB(pN, 1, S1_0, S1_1, S1_2, S1_3, S1_4, S1_5);
                writeA(As[1]);
            }
            __syncthreads();
            pB = pN;
            tap_c = tap_n; c0_c = c0_n;
        }
        // ---------------- odd step s = sp+1 (computes As[1], S2/S1) ----------------
        {
            int s = sp + 1;
            if (s >= NT) break;
            int tap_n = tap_c, c0_n = c0_c + 64;
            if (c0_n == CC) { c0_n = 0; ++tap_n; }
            bool more = (s + 1 < NT);
            const unsigned short* pN = pB + STEPOFF;
            if (more) {
                LOADB(pN, 0, S0_0, S0_1, S0_2, S0_3, S0_4, S0_5);
                loadA(tap_n, c0_n);
            }
            __builtin_amdgcn_sched_barrier(0);
            COMPUTE_KS(As[1], 0, S2_0, S2_1, S2_2, S2_3, S2_4, S2_5);
            COMPUTE_KS(As[1], 1, S1_0, S1_1, S1_2, S1_3, S1_4, S1_5);
            __builtin_amdgcn_sched_barrier(0);
            if (more) {
                LOADB(pN, 1, S1_0, S1_1, S1_2, S1_3, S1_4, S1_5);
                writeA(As[0]);
            }
            __syncthreads();
            pB = pN;
            tap_c = tap_n; c0_c = c0_n;
        }
    }

    // epilogue: + residual
    int lr4 = (lane >> 4) * 4, lc = lane & 15;
#pragma unroll
    for (int m = 0; m < 4; ++m) {
        int gr = r0 + m * 16 + lr4;
#pragma unroll
        for (int n = 0; n < 6; ++n) {
            int gc = o0 + wc * 96 + n * 16 + lc;
#pragma unroll
            for (int j = 0; j < 4; ++j) {
                size_t idx = (size_t)(gr + j) * CC + gc;
                out[idx] = acc[m][n][j] + resid[idx];
            }
        }
    }
}

extern "C" void kernel_launch(void* const* d_in, const int* in_sizes, int n_in,
                              void* d_out, int out_size, void* d_ws, size_t ws_size,
                              hipStream_t stream) {
    const float* x   = (const float*)d_in[0];
    const float* am  = (const float*)d_in[1];
    const float* stm = (const float*)d_in[2];
    const float* lnw = (const float*)d_in[3];
    const float* lnb = (const float*)d_in[4];
    const float* ow  = (const float*)d_in[5];
    const float* ob  = (const float*)d_in[6];
    const float* mw  = (const float*)d_in[7];
    const float* mb  = (const float*)d_in[8];
    const float* rw  = (const float*)d_in[9];
    float* out = (float*)d_out;

    char* ws = (char*)d_ws;
    size_t off = 0;
    auto carve = [&](size_t bytes) -> char* {
        char* p = ws + off;
        off += (bytes + 255) & ~(size_t)255;
        return p;
    };
    unsigned short* hb  = (unsigned short*)carve((size_t)ROWS * CC * 2);   // 25.2 MB
    unsigned short* wbt = (unsigned short*)carve((size_t)NKC * CC * 8 * 2);// 8.25 MB
    unsigned short* wcb = (unsigned short*)carve((size_t)128 * CC * 2);    // 0.20 MB
    float* d    = (float*)carve((size_t)ROWS * 128 * 4);                   // 8.4 MB
    float* gate = (float*)carve((size_t)ROWS * 4);
    int*   i0   = (int*)carve((size_t)NKP * 4);
    int*   i1   = (int*)carve((size_t)NKP * 4);
    float* w0   = (float*)carve((size_t)NKP * 4);
    float* w1   = (float*)carve((size_t)NKP * 4);

    k_ln<<<ROWS, 256, 0, stream>>>(x, am, stm, lnw, lnb, hb, gate);
    k_wbt<<<CC, 256, 0, stream>>>(rw, wbt);
    k_wcb<<<128, 256, 0, stream>>>(ow, mw, wcb);
    k_dg2<<<ROWS / 128, 256, 0, stream>>>(hb, wcb, d);
    k_off<<<NKP / 256, 256, 0, stream>>>(d, ob, mb, gate, i0, i1, w0, w1);
    k_fgemm<<<512, 256, 0, stream>>>(hb, wbt, i0, i1, w0, w1, x, out);
}

// Round 11
// 206.375 us; speedup vs baseline: 1.2731x; 1.0013x over previous
//
#include <hip/hip_runtime.h>
#include <math.h>

#define BB 4
#define LL 4096
#define CC 768
#define KHH 7
#define PADK 3
#define ROWS (BB*LL)      // 16384
#define NKP  (BB*KHH*LL)  // 114688
#define GK   (KHH*CC)     // 5376
#define NT   (GK/64)      // 84
#define NKC  (GK/8)       // 672

typedef unsigned short ushort8 __attribute__((ext_vector_type(8)));
typedef short short8 __attribute__((ext_vector_type(8)));
typedef float f32x4 __attribute__((ext_vector_type(4)));

__device__ __forceinline__ float bf2f(unsigned short u) {
    return __uint_as_float(((unsigned)u) << 16);
}
__device__ __forceinline__ unsigned short f2bf(float x) {
    unsigned u = __float_as_uint(x);
    return (unsigned short)((u + 0x7FFFu + ((u >> 16) & 1u)) >> 16);
}

// ---------------- K1: layernorm + gate -> h_bf16 ----------------
__global__ __launch_bounds__(256) void k_ln(const float* __restrict__ x,
        const float* __restrict__ mask, const float* __restrict__ special,
        const float* __restrict__ lnw, const float* __restrict__ lnb,
        unsigned short* __restrict__ hb, float* __restrict__ gate) {
    int row = blockIdx.x;
    const float* xr = x + (size_t)row * CC;
    float s = 0.f, q = 0.f;
    for (int i = threadIdx.x; i < CC; i += 256) { float v = xr[i]; s += v; q += v * v; }
    for (int o = 32; o; o >>= 1) { s += __shfl_xor(s, o); q += __shfl_xor(q, o); }
    __shared__ float ss[4], sq[4];
    int wid = threadIdx.x >> 6;
    if ((threadIdx.x & 63) == 0) { ss[wid] = s; sq[wid] = q; }
    __syncthreads();
    s = ss[0] + ss[1] + ss[2] + ss[3];
    q = sq[0] + sq[1] + sq[2] + sq[3];
    float mu  = s * (1.f / CC);
    float var = fmaxf(q * (1.f / CC) - mu * mu, 0.f);
    float rstd = rsqrtf(var + 1e-12f);
    unsigned short* hr = hb + (size_t)row * CC;
    for (int i = threadIdx.x; i < CC; i += 256)
        hr[i] = f2bf((xr[i] - mu) * rstd * lnw[i] + lnb[i]);
    if (threadIdx.x == 0) gate[row] = (1.f - special[row]) * mask[row];
}

// ---------------- K2: reg_w[o][c][k] -> Wbt[kc][o][e] bf16  (kc = K/8, K = k*768+c) ----------------
__global__ __launch_bounds__(256) void k_wbt(const float* __restrict__ rw,
                                             unsigned short* __restrict__ wbt) {
    __shared__ float s[GK];
    int o = blockIdx.x;
    for (int i = threadIdx.x; i < GK; i += 256) s[i] = rw[(size_t)o * GK + i];
    __syncthreads();
    for (int kc = threadIdx.x; kc < NKC; kc += 256) {
        int k = kc / 96;               // tap
        int c0 = (kc - k * 96) * 8;    // channel base
        ushort8 r;
#pragma unroll
        for (int e = 0; e < 8; ++e) r[e] = f2bf(s[(c0 + e) * KHH + k]);
        *(ushort8*)(wbt + ((size_t)kc * CC + o) * 8) = r;
    }
}

// ---------------- K2b: conv weights -> wcb[i][c] bf16 ----------------
__global__ __launch_bounds__(256) void k_wcb(const float* __restrict__ ow, const float* __restrict__ mw,
                                             unsigned short* __restrict__ wcb) {
    int i = blockIdx.x;
    for (int c = threadIdx.x; c < CC; c += 256) {
        float v = 0.f;
        if (i < 49)      v = ow[(size_t)(i / 7) * (CC * KHH) + (size_t)c * KHH + (i % 7)];
        else if (i < 98) { int j = i - 49; v = mw[(size_t)(j / 7) * (CC * KHH) + (size_t)c * KHH + (j % 7)]; }
        wcb[(size_t)i * CC + c] = f2bf(v);
    }
}

// ---------------- K3: d[row][i] = sum_c hb[row][c] * wcb[i][c] ----------------
__global__ __launch_bounds__(256) void k_dg2(const unsigned short* __restrict__ A,
        const unsigned short* __restrict__ Bm, float* __restrict__ d) {
    __shared__ __align__(16) char As[128 * 128];
    __shared__ __align__(16) char Bs[128 * 128];
    int r0 = blockIdx.x * 128;
    int t = threadIdx.x;
    int lane = t & 63, w = t >> 6;
    int wr = w >> 1, wc = w & 1;
    f32x4 acc[4][4];
#pragma unroll
    for (int m = 0; m < 4; ++m)
#pragma unroll
        for (int n = 0; n < 4; ++n) acc[m][n] = (f32x4){0.f, 0.f, 0.f, 0.f};
    int lr = lane & 15;
    int lkb0 = (lane >> 4) * 16;
    for (int kk = 0; kk < CC; kk += 64) {
#pragma unroll
        for (int s = 0; s < 4; ++s) {
            int byteoff = (s * 256 + t) * 16;
            int row = byteoff >> 7;
            int colb = byteoff & 127;
            int sw = (row * 128 + colb) ^ ((row & 7) << 4);
            *(ushort8*)(As + sw) = *(const ushort8*)(A + (size_t)(r0 + row) * CC + kk + (colb >> 1));
            *(ushort8*)(Bs + sw) = *(const ushort8*)(Bm + (size_t)row * CC + kk + (colb >> 1));
        }
        __syncthreads();
#pragma unroll
        for (int ks = 0; ks < 2; ++ks) {
            short8 av[4], bv[4];
            int lkb = lkb0 + ks * 64;
#pragma unroll
            for (int m = 0; m < 4; ++m) {
                int ar = wr * 64 + m * 16 + lr;
                av[m] = *(const short8*)(As + ((ar * 128 + lkb) ^ ((ar & 7) << 4)));
            }
#pragma unroll
            for (int n = 0; n < 4; ++n) {
                int br = wc * 64 + n * 16 + lr;
                bv[n] = *(const short8*)(Bs + ((br * 128 + lkb) ^ ((br & 7) << 4)));
            }
#pragma unroll
            for (int m = 0; m < 4; ++m)
#pragma unroll
                for (int n = 0; n < 4; ++n)
                    acc[m][n] = __builtin_amdgcn_mfma_f32_16x16x32_bf16(av[m], bv[n], acc[m][n], 0, 0, 0);
        }
        __syncthreads();
    }
    int lr4 = (lane >> 4) * 4, lc = lane & 15;
#pragma unroll
    for (int m = 0; m < 4; ++m) {
        int gr = r0 + wr * 64 + m * 16 + lr4;
#pragma unroll
        for (int n = 0; n < 4; ++n) {
            int gc = wc * 64 + n * 16 + lc;
#pragma unroll
            for (int j = 0; j < 4; ++j)
                d[(size_t)(gr + j) * 128 + gc] = acc[m][n][j];
        }
    }
}

// ---------------- K4: sampling params ----------------
__global__ __launch_bounds__(256) void k_off(const float* __restrict__ d,
        const float* __restrict__ offb, const float* __restrict__ modb,
        const float* __restrict__ gate,
        int* __restrict__ idx0, int* __restrict__ idx1,
        float* __restrict__ w0a, float* __restrict__ w1a) {
    int flat = blockIdx.x * 256 + threadIdx.x;   // b*7*L + k*L + p
    if (flat >= NKP) return;
    int p = flat & (LL - 1);
    int k = (flat >> 12) % KHH;
    int b = flat / (KHH * LL);
    float offa = offb[k], moda = modb[k];
#pragma unroll
    for (int j = 0; j < KHH; ++j) {
        int q = p + j - PADK;
        if (q >= 0 && q < LL) {
            const float* dr = d + (size_t)(b * LL + q) * 128;
            offa += dr[k * 7 + j];
            moda += dr[49 + k * 7 + j];
        }
    }
    float modv = 2.f / (1.f + expf(-moda));
    float pos = (float)(p - PADK + k) + offa;
    pos = fminf(fmaxf(pos, -1.0e9f), 1.0e9f);
    float f = floorf(pos);
    float tf = pos - f;
    int i0 = (int)f;
    int i1 = i0 + 1;
    float in0 = (i0 >= 0 && i0 < LL) ? 1.f : 0.f;
    float in1 = (i1 >= 0 && i1 < LL) ? 1.f : 0.f;
    int c0 = min(max(i0, 0), LL - 1);
    int c1 = min(max(i1, 0), LL - 1);
    float g0 = gate[b * LL + c0] * in0;
    float g1 = gate[b * LL + c1] * in1;
    w0a[flat] = modv * (1.f - tf) * g0;
    w1a[flat] = modv * tf * g1;
    idx0[flat] = c0;
    idx1[flat] = c1;
}

// ---------------- K5: fused sample+GEMM; BM=64, 4 waves, 2 blocks/CU, counted-vmcnt barrier ----------------
// BM=64, BN=384, BK=64; 256 threads = 4 waves (1x4), wave tile 64x96 = 4x6 frags 16x16x32

#define STEPOFF 49152   // 8 kc per step * 768 * 8 elems
#define KSOFF   24576   // 4 kc * 768 * 8 elems

#define LOADB(Q, KS, D0, D1, D2, D3, D4, D5) do { \
    const unsigned short* _q = (Q) + (KS) * KSOFF; \
    D0 = *(const short8*)(_q); \
    D1 = *(const short8*)(_q + 128); \
    D2 = *(const short8*)(_q + 256); \
    D3 = *(const short8*)(_q + 384); \
    D4 = *(const short8*)(_q + 512); \
    D5 = *(const short8*)(_q + 640); \
} while (0)

#define MFMA_ROW(AV, M, B0, B1, B2, B3, B4, B5) \
    acc[M][0] = __builtin_amdgcn_mfma_f32_16x16x32_bf16(AV, B0, acc[M][0], 0, 0, 0); \
    acc[M][1] = __builtin_amdgcn_mfma_f32_16x16x32_bf16(AV, B1, acc[M][1], 0, 0, 0); \
    acc[M][2] = __builtin_amdgcn_mfma_f32_16x16x32_bf16(AV, B2, acc[M][2], 0, 0, 0); \
    acc[M][3] = __builtin_amdgcn_mfma_f32_16x16x32_bf16(AV, B3, acc[M][3], 0, 0, 0); \
    acc[M][4] = __builtin_amdgcn_mfma_f32_16x16x32_bf16(AV, B4, acc[M][4], 0, 0, 0); \
    acc[M][5] = __builtin_amdgcn_mfma_f32_16x16x32_bf16(AV, B5, acc[M][5], 0, 0, 0);

#define COMPUTE_KS(ASB, KS, B0, B1, B2, B3, B4, B5) do { \
    __builtin_amdgcn_s_setprio(1); \
    int _lkb = ke0 * 2 + (KS) * 64; \
    short8 _av0, _av1, _av2, _av3; \
    { int ar = 0 * 16 + lr; _av0 = *(const short8*)((ASB) + ar * 128 + (_lkb ^ ((ar & 7) << 4))); } \
    { int ar = 1 * 16 + lr; _av1 = *(const short8*)((ASB) + ar * 128 + (_lkb ^ ((ar & 7) << 4))); } \
    { int ar = 2 * 16 + lr; _av2 = *(const short8*)((ASB) + ar * 128 + (_lkb ^ ((ar & 7) << 4))); } \
    { int ar = 3 * 16 + lr; _av3 = *(const short8*)((ASB) + ar * 128 + (_lkb ^ ((ar & 7) << 4))); } \
    MFMA_ROW(_av0, 0, B0, B1, B2, B3, B4, B5) \
    MFMA_ROW(_av1, 1, B0, B1, B2, B3, B4, B5) \
    MFMA_ROW(_av2, 2, B0, B1, B2, B3, B4, B5) \
    MFMA_ROW(_av3, 3, B0, B1, B2, B3, B4, B5) \
    __builtin_amdgcn_s_setprio(0); \
} while (0)

// counted barrier (T4): LDS drained, global loads stay in flight across the barrier
#define BAR() do { \
    asm volatile("s_waitcnt lgkmcnt(0)" ::: "memory"); \
    __builtin_amdgcn_s_barrier(); \
    __builtin_amdgcn_sched_barrier(0); \
} while (0)

__global__ __launch_bounds__(256, 2) void k_fgemm(const unsigned short* __restrict__ hb,
        const unsigned short* __restrict__ Wbt,
        const int* __restrict__ idx0, const int* __restrict__ idx1,
        const float* __restrict__ w0a, const float* __restrict__ w1a,
        const float* __restrict__ resid, float* __restrict__ out) {
    __shared__ __align__(16) char As[2][64 * 128];

    int bid = blockIdx.x;
    int nhalf = (bid & 7) >> 2;                 // XCDs 0-3 -> half 0, 4-7 -> half 1
    int rowtile = (bid >> 3) * 4 + (bid & 3);   // bijective 0..255
    int r0 = rowtile * 64;
    int o0 = nhalf * 384;
    int b = r0 >> 12;
    int p0 = r0 & (LL - 1);
    int pbase = ((b * KHH) << 12) + p0;
    const unsigned short* hbB = hb + (size_t)b * LL * CC;

    int t = threadIdx.x;
    int lane = t & 63, wc = t >> 6;             // wave 0..3 owns 96-col strip
    int lr = lane & 15;
    int ke0 = (lane >> 4) * 8;     // elem offset of lane's 8-elem k-chunk

    // per-lane B base pointer into Wbt; advances STEPOFF per step
    const unsigned short* pB = Wbt + ((size_t)(lane >> 4) * CC + o0 + wc * 96 + lr) * 8;

    // A-build mapping: row = t>>2 (0..63), seg = t&3 (16 elems each)
    int arow = t >> 2, aseg = t & 3;
    int acolb = aseg * 32;
    int aswz0 = arow * 128 + (acolb ^ ((arow & 7) << 4));
    int aswz1 = arow * 128 + ((acolb + 16) ^ ((arow & 7) << 4));

    f32x4 acc[4][6];
#pragma unroll
    for (int m = 0; m < 4; ++m)
#pragma unroll
        for (int n = 0; n < 6; ++n) acc[m][n] = (f32x4){0.f, 0.f, 0.f, 0.f};

    // per-tap sampling regs
    int g0 = 0, g1 = 0;
    float wa = 0.f, wbv = 0.f;
    int cur_tap = -1;

    // staging registers (all individually named)
    ushort8 la0, la1, la2, la3;
    short8 S0_0, S0_1, S0_2, S0_3, S0_4, S0_5;   // ks0 buffer (even steps)
    short8 S1_0, S1_1, S1_2, S1_3, S1_4, S1_5;   // ks1 buffer (reloaded late every step)
    short8 S2_0, S2_1, S2_2, S2_3, S2_4, S2_5;   // ks0 buffer (odd steps)

    auto loadA = [&](int tap, int c0) {
        if (tap != cur_tap) {
            int pf = pbase + (tap << 12) + arow;
            g0 = idx0[pf]; g1 = idx1[pf];
            wa = w0a[pf];  wbv = w1a[pf];
            cur_tap = tap;
        }
        const unsigned short* s0 = hbB + (size_t)g0 * CC + c0 + aseg * 16;
        const unsigned short* s1 = hbB + (size_t)g1 * CC + c0 + aseg * 16;
        la0 = *(const ushort8*)(s0);
        la1 = *(const ushort8*)(s0 + 8);
        la2 = *(const ushort8*)(s1);
        la3 = *(const ushort8*)(s1 + 8);
    };

    auto writeA = [&](char* Asb) {
        ushort8 ra, rb;
#pragma unroll
        for (int e = 0; e < 8; ++e) ra[e] = f2bf(fmaf(wa, bf2f(la0[e]), wbv * bf2f(la2[e])));
#pragma unroll
        for (int e = 0; e < 8; ++e) rb[e] = f2bf(fmaf(wa, bf2f(la1[e]), wbv * bf2f(la3[e])));
        *(ushort8*)(Asb + aswz0) = ra;
        *(ushort8*)(Asb + aswz1) = rb;
    };

    // prologue: step 0 fully staged
    loadA(0, 0);
    LOADB(pB, 0, S0_0, S0_1, S0_2, S0_3, S0_4, S0_5);
    LOADB(pB, 1, S1_0, S1_1, S1_2, S1_3, S1_4, S1_5);
    writeA(As[0]);
    BAR();

    int tap_c = 0, c0_c = 0;
    for (int sp = 0; sp < NT; sp += 2) {
        // ---------------- even step s = sp (computes As[0], S0/S1) ----------------
        {
            int tap_n = tap_c, c0_n = c0_c + 64;
            if (c0_n == CC) { c0_n = 0; ++tap_n; }
            bool more = (sp + 1 < NT);
            const unsigned short* pN = pB + STEPOFF;
            if (more) {
                LOADB(pN, 0, S2_0, S2_1, S2_2, S2_3, S2_4, S2_5);
                loadA(tap_n, c0_n);
            }
            __builtin_amdgcn_sched_barrier(0);
            COMPUTE_KS(As[0], 0, S0_0, S0_1, S0_2, S0_3, S0_4, S0_5);
            COMPUTE_KS(As[0], 1, S1_0, S1_1, S1_2, S1_3, S1_4, S1_5);
            __builtin_amdgcn_sched_barrier(0);
            if (more) {
                LOADB(pN, 1, S1_0, S1_1, S1_2, S1_3, S1_4, S1_5);
                writeA(As[1]);
            }
            BAR();
            pB = pN;
            tap_c = tap_n; c0_c = c0_n;
        }
        // ---------------- odd step s = sp+1 (computes As[1], S2/S1) ----------------
        {
            int s = sp + 1;
            if (s >= NT) break;
            int tap_n = tap_c, c0_n = c0_c + 64;
            if (c0_n == CC) { c0_n = 0; ++tap_n; }
            bool more = (s + 1 < NT);
            const unsigned short* pN = pB + STEPOFF;
            if (more) {
                LOADB(pN, 0, S0_0, S0_1, S0_2, S0_3, S0_4, S0_5);
                loadA(tap_n, c0_n);
            }
            __builtin_amdgcn_sched_barrier(0);
            COMPUTE_KS(As[1], 0, S2_0, S2_1, S2_2, S2_3, S2_4, S2_5);
            COMPUTE_KS(As[1], 1, S1_0, S1_1, S1_2, S1_3, S1_4, S1_5);
            __builtin_amdgcn_sched_barrier(0);
            if (more) {
                LOADB(pN, 1, S1_0, S1_1, S1_2, S1_3, S1_4, S1_5);
                writeA(As[0]);
            }
            BAR();
            pB = pN;
            tap_c = tap_n; c0_c = c0_n;
        }
    }

    // epilogue: + residual
    int lr4 = (lane >> 4) * 4, lc = lane & 15;
#pragma unroll
    for (int m = 0; m < 4; ++m) {
        int gr = r0 + m * 16 + lr4;
#pragma unroll
        for (int n = 0; n < 6; ++n) {
            int gc = o0 + wc * 96 + n * 16 + lc;
#pragma unroll
            for (int j = 0; j < 4; ++j) {
                size_t idx = (size_t)(gr + j) * CC + gc;
                out[idx] = acc[m][n][j] + resid[idx];
            }
        }
    }
}

extern "C" void kernel_launch(void* const* d_in, const int* in_sizes, int n_in,
                              void* d_out, int out_size, void* d_ws, size_t ws_size,
                              hipStream_t stream) {
    const float* x   = (const float*)d_in[0];
    const float* am  = (const float*)d_in[1];
    const float* stm = (const float*)d_in[2];
    const float* lnw = (const float*)d_in[3];
    const float* lnb = (const float*)d_in[4];
    const float* ow  = (const float*)d_in[5];
    const float* ob  = (const float*)d_in[6];
    const float* mw  = (const float*)d_in[7];
    const float* mb  = (const float*)d_in[8];
    const float* rw  = (const float*)d_in[9];
    float* out = (float*)d_out;

    char* ws = (char*)d_ws;
    size_t off = 0;
    auto carve = [&](size_t bytes) -> char* {
        char* p = ws + off;
        off += (bytes + 255) & ~(size_t)255;
        return p;
    };
    unsigned short* hb  = (unsigned short*)carve((size_t)ROWS * CC * 2);   // 25.2 MB
    unsigned short* wbt = (unsigned short*)carve((size_t)NKC * CC * 8 * 2);// 8.25 MB
    unsigned short* wcb = (unsigned short*)carve((size_t)128 * CC * 2);    // 0.20 MB
    float* d    = (float*)carve((size_t)ROWS * 128 * 4);                   // 8.4 MB
    float* gate = (float*)carve((size_t)ROWS * 4);
    int*   i0   = (int*)carve((size_t)NKP * 4);
    int*   i1   = (int*)carve((size_t)NKP * 4);
    float* w0   = (float*)carve((size_t)NKP * 4);
    float* w1   = (float*)carve((size_t)NKP * 4);

    k_ln<<<ROWS, 256, 0, stream>>>(x, am, stm, lnw, lnb, hb, gate);
    k_wbt<<<CC, 256, 0, stream>>>(rw, wbt);
    k_wcb<<<128, 256, 0, stream>>>(ow, mw, wcb);
    k_dg2<<<ROWS / 128, 256, 0, stream>>>(hb, wcb, d);
    k_off<<<NKP / 256, 256, 0, stream>>>(d, ob, mb, gate, i0, i1, w0, w1);
    k_fgemm<<<512, 256, 0, stream>>>(hb, wbt, i0, i1, w0, w1, x, out);
}

// Round 12
// 203.533 us; speedup vs baseline: 1.2909x; 1.0140x over previous
//
#include <hip/hip_runtime.h>
#include <math.h>

#define BB 4
#define LL 4096
#define CC 768
#define KHH 7
#define PADK 3
#define ROWS (BB*LL)      // 16384
#define NKP  (BB*KHH*LL)  // 114688
#define GK   (KHH*CC)     // 5376
#define NT   (GK/64)      // 84
#define NKC  (GK/8)       // 672

typedef unsigned short ushort8 __attribute__((ext_vector_type(8)));
typedef short short8 __attribute__((ext_vector_type(8)));
typedef float f32x4 __attribute__((ext_vector_type(4)));

__device__ __forceinline__ float bf2f(unsigned short u) {
    return __uint_as_float(((unsigned)u) << 16);
}
__device__ __forceinline__ unsigned short f2bf(float x) {
    unsigned u = __float_as_uint(x);
    return (unsigned short)((u + 0x7FFFu + ((u >> 16) & 1u)) >> 16);
}

// ---------------- K1: layernorm + gate -> h_bf16 ----------------
__global__ __launch_bounds__(256) void k_ln(const float* __restrict__ x,
        const float* __restrict__ mask, const float* __restrict__ special,
        const float* __restrict__ lnw, const float* __restrict__ lnb,
        unsigned short* __restrict__ hb, float* __restrict__ gate) {
    int row = blockIdx.x;
    const float* xr = x + (size_t)row * CC;
    float s = 0.f, q = 0.f;
    for (int i = threadIdx.x; i < CC; i += 256) { float v = xr[i]; s += v; q += v * v; }
    for (int o = 32; o; o >>= 1) { s += __shfl_xor(s, o); q += __shfl_xor(q, o); }
    __shared__ float ss[4], sq[4];
    int wid = threadIdx.x >> 6;
    if ((threadIdx.x & 63) == 0) { ss[wid] = s; sq[wid] = q; }
    __syncthreads();
    s = ss[0] + ss[1] + ss[2] + ss[3];
    q = sq[0] + sq[1] + sq[2] + sq[3];
    float mu  = s * (1.f / CC);
    float var = fmaxf(q * (1.f / CC) - mu * mu, 0.f);
    float rstd = rsqrtf(var + 1e-12f);
    unsigned short* hr = hb + (size_t)row * CC;
    for (int i = threadIdx.x; i < CC; i += 256)
        hr[i] = f2bf((xr[i] - mu) * rstd * lnw[i] + lnb[i]);
    if (threadIdx.x == 0) gate[row] = (1.f - special[row]) * mask[row];
}

// ---------------- K2: reg_w[o][c][k] -> Wbt[kc][o][e] bf16  (kc = K/8, K = k*768+c) ----------------
__global__ __launch_bounds__(256) void k_wbt(const float* __restrict__ rw,
                                             unsigned short* __restrict__ wbt) {
    __shared__ float s[GK];
    int o = blockIdx.x;
    for (int i = threadIdx.x; i < GK; i += 256) s[i] = rw[(size_t)o * GK + i];
    __syncthreads();
    for (int kc = threadIdx.x; kc < NKC; kc += 256) {
        int k = kc / 96;               // tap
        int c0 = (kc - k * 96) * 8;    // channel base
        ushort8 r;
#pragma unroll
        for (int e = 0; e < 8; ++e) r[e] = f2bf(s[(c0 + e) * KHH + k]);
        *(ushort8*)(wbt + ((size_t)kc * CC + o) * 8) = r;
    }
}

// ---------------- K2b: conv weights -> wcb[i][c] bf16 ----------------
__global__ __launch_bounds__(256) void k_wcb(const float* __restrict__ ow, const float* __restrict__ mw,
                                             unsigned short* __restrict__ wcb) {
    int i = blockIdx.x;
    for (int c = threadIdx.x; c < CC; c += 256) {
        float v = 0.f;
        if (i < 49)      v = ow[(size_t)(i / 7) * (CC * KHH) + (size_t)c * KHH + (i % 7)];
        else if (i < 98) { int j = i - 49; v = mw[(size_t)(j / 7) * (CC * KHH) + (size_t)c * KHH + (j % 7)]; }
        wcb[(size_t)i * CC + c] = f2bf(v);
    }
}

// ---------------- K3: d[row][i] = sum_c hb[row][c] * wcb[i][c] ----------------
__global__ __launch_bounds__(256) void k_dg2(const unsigned short* __restrict__ A,
        const unsigned short* __restrict__ Bm, float* __restrict__ d) {
    __shared__ __align__(16) char As[128 * 128];
    __shared__ __align__(16) char Bs[128 * 128];
    int r0 = blockIdx.x * 128;
    int t = threadIdx.x;
    int lane = t & 63, w = t >> 6;
    int wr = w >> 1, wc = w & 1;
    f32x4 acc[4][4];
#pragma unroll
    for (int m = 0; m < 4; ++m)
#pragma unroll
        for (int n = 0; n < 4; ++n) acc[m][n] = (f32x4){0.f, 0.f, 0.f, 0.f};
    int lr = lane & 15;
    int lkb0 = (lane >> 4) * 16;
    for (int kk = 0; kk < CC; kk += 64) {
#pragma unroll
        for (int s = 0; s < 4; ++s) {
            int byteoff = (s * 256 + t) * 16;
            int row = byteoff >> 7;
            int colb = byteoff & 127;
            int sw = (row * 128 + colb) ^ ((row & 7) << 4);
            *(ushort8*)(As + sw) = *(const ushort8*)(A + (size_t)(r0 + row) * CC + kk + (colb >> 1));
            *(ushort8*)(Bs + sw) = *(const ushort8*)(Bm + (size_t)row * CC + kk + (colb >> 1));
        }
        __syncthreads();
#pragma unroll
        for (int ks = 0; ks < 2; ++ks) {
            short8 av[4], bv[4];
            int lkb = lkb0 + ks * 64;
#pragma unroll
            for (int m = 0; m < 4; ++m) {
                int ar = wr * 64 + m * 16 + lr;
                av[m] = *(const short8*)(As + ((ar * 128 + lkb) ^ ((ar & 7) << 4)));
            }
#pragma unroll
            for (int n = 0; n < 4; ++n) {
                int br = wc * 64 + n * 16 + lr;
                bv[n] = *(const short8*)(Bs + ((br * 128 + lkb) ^ ((br & 7) << 4)));
            }
#pragma unroll
            for (int m = 0; m < 4; ++m)
#pragma unroll
                for (int n = 0; n < 4; ++n)
                    acc[m][n] = __builtin_amdgcn_mfma_f32_16x16x32_bf16(av[m], bv[n], acc[m][n], 0, 0, 0);
        }
        __syncthreads();
    }
    int lr4 = (lane >> 4) * 4, lc = lane & 15;
#pragma unroll
    for (int m = 0; m < 4; ++m) {
        int gr = r0 + wr * 64 + m * 16 + lr4;
#pragma unroll
        for (int n = 0; n < 4; ++n) {
            int gc = wc * 64 + n * 16 + lc;
#pragma unroll
            for (int j = 0; j < 4; ++j)
                d[(size_t)(gr + j) * 128 + gc] = acc[m][n][j];
        }
    }
}

// ---------------- K4: sampling params ----------------
__global__ __launch_bounds__(256) void k_off(const float* __restrict__ d,
        const float* __restrict__ offb, const float* __restrict__ modb,
        const float* __restrict__ gate,
        int* __restrict__ idx0, int* __restrict__ idx1,
        float* __restrict__ w0a, float* __restrict__ w1a) {
    int flat = blockIdx.x * 256 + threadIdx.x;   // b*7*L + k*L + p
    if (flat >= NKP) return;
    int p = flat & (LL - 1);
    int k = (flat >> 12) % KHH;
    int b = flat / (KHH * LL);
    float offa = offb[k], moda = modb[k];
#pragma unroll
    for (int j = 0; j < KHH; ++j) {
        int q = p + j - PADK;
        if (q >= 0 && q < LL) {
            const float* dr = d + (size_t)(b * LL + q) * 128;
            offa += dr[k * 7 + j];
            moda += dr[49 + k * 7 + j];
        }
    }
    float modv = 2.f / (1.f + expf(-moda));
    float pos = (float)(p - PADK + k) + offa;
    pos = fminf(fmaxf(pos, -1.0e9f), 1.0e9f);
    float f = floorf(pos);
    float tf = pos - f;
    int i0 = (int)f;
    int i1 = i0 + 1;
    float in0 = (i0 >= 0 && i0 < LL) ? 1.f : 0.f;
    float in1 = (i1 >= 0 && i1 < LL) ? 1.f : 0.f;
    int c0 = min(max(i0, 0), LL - 1);
    int c1 = min(max(i1, 0), LL - 1);
    float g0 = gate[b * LL + c0] * in0;
    float g1 = gate[b * LL + c1] * in1;
    w0a[flat] = modv * (1.f - tf) * g0;
    w1a[flat] = modv * tf * g1;
    idx0[flat] = c0;
    idx1[flat] = c1;
}

// ---------------- K5: fused sample+GEMM; 8 waves x (128x48 strip), no B duplication ----------------
// BM=128, BN=384, BK=64; 512 threads = 8 waves (1x8), wave strip 128x48 = 8x3 frags 16x16x32

#define STEPOFF 49152   // 8 kc per step * 768 * 8 elems
#define KSOFF   24576   // 4 kc * 768 * 8 elems

#define LOADB3(Q, KS, D0, D1, D2) do { \
    const unsigned short* _q = (Q) + (KS) * KSOFF; \
    D0 = *(const short8*)(_q); \
    D1 = *(const short8*)(_q + 128); \
    D2 = *(const short8*)(_q + 256); \
} while (0)

#define MFMA_ROW3(AV, M, B0, B1, B2) \
    acc[M][0] = __builtin_amdgcn_mfma_f32_16x16x32_bf16(AV, B0, acc[M][0], 0, 0, 0); \
    acc[M][1] = __builtin_amdgcn_mfma_f32_16x16x32_bf16(AV, B1, acc[M][1], 0, 0, 0); \
    acc[M][2] = __builtin_amdgcn_mfma_f32_16x16x32_bf16(AV, B2, acc[M][2], 0, 0, 0);

#define COMPUTE_KS3(ASB, KS, B0, B1, B2) do { \
    __builtin_amdgcn_s_setprio(1); \
    int _lkb = ke0 * 2 + (KS) * 64; \
    short8 _av0, _av1, _av2, _av3, _av4, _av5, _av6, _av7; \
    { int ar = 0 * 16 + lr; _av0 = *(const short8*)((ASB) + ar * 128 + (_lkb ^ ((ar & 7) << 4))); } \
    { int ar = 1 * 16 + lr; _av1 = *(const short8*)((ASB) + ar * 128 + (_lkb ^ ((ar & 7) << 4))); } \
    { int ar = 2 * 16 + lr; _av2 = *(const short8*)((ASB) + ar * 128 + (_lkb ^ ((ar & 7) << 4))); } \
    { int ar = 3 * 16 + lr; _av3 = *(const short8*)((ASB) + ar * 128 + (_lkb ^ ((ar & 7) << 4))); } \
    MFMA_ROW3(_av0, 0, B0, B1, B2) \
    MFMA_ROW3(_av1, 1, B0, B1, B2) \
    MFMA_ROW3(_av2, 2, B0, B1, B2) \
    MFMA_ROW3(_av3, 3, B0, B1, B2) \
    { int ar = 4 * 16 + lr; _av4 = *(const short8*)((ASB) + ar * 128 + (_lkb ^ ((ar & 7) << 4))); } \
    { int ar = 5 * 16 + lr; _av5 = *(const short8*)((ASB) + ar * 128 + (_lkb ^ ((ar & 7) << 4))); } \
    { int ar = 6 * 16 + lr; _av6 = *(const short8*)((ASB) + ar * 128 + (_lkb ^ ((ar & 7) << 4))); } \
    { int ar = 7 * 16 + lr; _av7 = *(const short8*)((ASB) + ar * 128 + (_lkb ^ ((ar & 7) << 4))); } \
    MFMA_ROW3(_av4, 4, B0, B1, B2) \
    MFMA_ROW3(_av5, 5, B0, B1, B2) \
    MFMA_ROW3(_av6, 6, B0, B1, B2) \
    MFMA_ROW3(_av7, 7, B0, B1, B2) \
    __builtin_amdgcn_s_setprio(0); \
} while (0)

// counted barrier (T4): LDS drained, global loads stay in flight across the barrier
#define BAR() do { \
    asm volatile("s_waitcnt lgkmcnt(0)" ::: "memory"); \
    __builtin_amdgcn_s_barrier(); \
    __builtin_amdgcn_sched_barrier(0); \
} while (0)

__global__ __launch_bounds__(512, 2) void k_fgemm(const unsigned short* __restrict__ hb,
        const unsigned short* __restrict__ Wbt,
        const int* __restrict__ idx0, const int* __restrict__ idx1,
        const float* __restrict__ w0a, const float* __restrict__ w1a,
        const float* __restrict__ resid, float* __restrict__ out) {
    __shared__ __align__(16) char As[2][128 * 128];

    int bid = blockIdx.x;
    int nhalf = (bid & 7) >> 2;                 // XCDs 0-3 -> half 0, 4-7 -> half 1
    int rowtile = (bid >> 3) * 4 + (bid & 3);   // bijective 0..127
    int r0 = rowtile * 128;
    int o0 = nhalf * 384;
    int b = r0 >> 12;
    int p0 = r0 & (LL - 1);
    int pbase = ((b * KHH) << 12) + p0;
    const unsigned short* hbB = hb + (size_t)b * LL * CC;

    int t = threadIdx.x;
    int lane = t & 63, wc = t >> 6;             // wave 0..7 owns 48-col strip
    int lr = lane & 15;
    int ke0 = (lane >> 4) * 8;     // elem offset of lane's 8-elem k-chunk

    // per-lane B base pointer into Wbt; advances STEPOFF per step
    const unsigned short* pB = Wbt + ((size_t)(lane >> 4) * CC + o0 + wc * 48 + lr) * 8;

    // A-build mapping: row = t>>2 (0..127), seg = t&3 (16 elems each)
    int arow = t >> 2, aseg = t & 3;
    int acolb = aseg * 32;
    int aswz0 = arow * 128 + (acolb ^ ((arow & 7) << 4));
    int aswz1 = arow * 128 + ((acolb + 16) ^ ((arow & 7) << 4));

    f32x4 acc[8][3];
#pragma unroll
    for (int m = 0; m < 8; ++m)
#pragma unroll
        for (int n = 0; n < 3; ++n) acc[m][n] = (f32x4){0.f, 0.f, 0.f, 0.f};

    // per-tap sampling regs
    int g0 = 0, g1 = 0;
    float wa = 0.f, wbv = 0.f;
    int cur_tap = -1;

    // staging registers (all individually named)
    ushort8 la0, la1, la2, la3;
    short8 S0_0, S0_1, S0_2;   // ks0 buffer (even steps)
    short8 S1_0, S1_1, S1_2;   // ks1 buffer (reloaded late every step)
    short8 S2_0, S2_1, S2_2;   // ks0 buffer (odd steps)

    auto loadA = [&](int tap, int c0) {
        if (tap != cur_tap) {
            int pf = pbase + (tap << 12) + arow;
            g0 = idx0[pf]; g1 = idx1[pf];
            wa = w0a[pf];  wbv = w1a[pf];
            cur_tap = tap;
        }
        const unsigned short* s0 = hbB + (size_t)g0 * CC + c0 + aseg * 16;
        const unsigned short* s1 = hbB + (size_t)g1 * CC + c0 + aseg * 16;
        la0 = *(const ushort8*)(s0);
        la1 = *(const ushort8*)(s0 + 8);
        la2 = *(const ushort8*)(s1);
        la3 = *(const ushort8*)(s1 + 8);
    };

    auto writeA = [&](char* Asb) {
        ushort8 ra, rb;
#pragma unroll
        for (int e = 0; e < 8; ++e) ra[e] = f2bf(fmaf(wa, bf2f(la0[e]), wbv * bf2f(la2[e])));
#pragma unroll
        for (int e = 0; e < 8; ++e) rb[e] = f2bf(fmaf(wa, bf2f(la1[e]), wbv * bf2f(la3[e])));
        *(ushort8*)(Asb + aswz0) = ra;
        *(ushort8*)(Asb + aswz1) = rb;
    };

    // prologue: step 0 fully staged
    loadA(0, 0);
    LOADB3(pB, 0, S0_0, S0_1, S0_2);
    LOADB3(pB, 1, S1_0, S1_1, S1_2);
    writeA(As[0]);
    BAR();

    int tap_c = 0, c0_c = 0;
    for (int sp = 0; sp < NT; sp += 2) {
        // ---------------- even step s = sp (computes As[0], S0/S1) ----------------
        {
            int tap_n = tap_c, c0_n = c0_c + 64;
            if (c0_n == CC) { c0_n = 0; ++tap_n; }
            bool more = (sp + 1 < NT);
            const unsigned short* pN = pB + STEPOFF;
            if (more) {
                LOADB3(pN, 0, S2_0, S2_1, S2_2);
                loadA(tap_n, c0_n);
            }
            __builtin_amdgcn_sched_barrier(0);
            COMPUTE_KS3(As[0], 0, S0_0, S0_1, S0_2);
            COMPUTE_KS3(As[0], 1, S1_0, S1_1, S1_2);
            __builtin_amdgcn_sched_barrier(0);
            if (more) {
                LOADB3(pN, 1, S1_0, S1_1, S1_2);
                writeA(As[1]);
            }
            BAR();
            pB = pN;
            tap_c = tap_n; c0_c = c0_n;
        }
        // ---------------- odd step s = sp+1 (computes As[1], S2/S1) ----------------
        {
            int s = sp + 1;
            if (s >= NT) break;
            int tap_n = tap_c, c0_n = c0_c + 64;
            if (c0_n == CC) { c0_n = 0; ++tap_n; }
            bool more = (s + 1 < NT);
            const unsigned short* pN = pB + STEPOFF;
            if (more) {
                LOADB3(pN, 0, S0_0, S0_1, S0_2);
                loadA(tap_n, c0_n);
            }
            __builtin_amdgcn_sched_barrier(0);
            COMPUTE_KS3(As[1], 0, S2_0, S2_1, S2_2);
            COMPUTE_KS3(As[1], 1, S1_0, S1_1, S1_2);
            __builtin_amdgcn_sched_barrier(0);
            if (more) {
                LOADB3(pN, 1, S1_0, S1_1, S1_2);
                writeA(As[0]);
            }
            BAR();
            pB = pN;
            tap_c = tap_n; c0_c = c0_n;
        }
    }

    // epilogue: + residual
    int lr4 = (lane >> 4) * 4, lc = lane & 15;
#pragma unroll
    for (int m = 0; m < 8; ++m) {
        int gr = r0 + m * 16 + lr4;
#pragma unroll
        for (int n = 0; n < 3; ++n) {
            int gc = o0 + wc * 48 + n * 16 + lc;
#pragma unroll
            for (int j = 0; j < 4; ++j) {
                size_t idx = (size_t)(gr + j) * CC + gc;
                out[idx] = acc[m][n][j] + resid[idx];
            }
        }
    }
}

extern "C" void kernel_launch(void* const* d_in, const int* in_sizes, int n_in,
                              void* d_out, int out_size, void* d_ws, size_t ws_size,
                              hipStream_t stream) {
    const float* x   = (const float*)d_in[0];
    const float* am  = (const float*)d_in[1];
    const float* stm = (const float*)d_in[2];
    const float* lnw = (const float*)d_in[3];
    const float* lnb = (const float*)d_in[4];
    const float* ow  = (const float*)d_in[5];
    const float* ob  = (const float*)d_in[6];
    const float* mw  = (const float*)d_in[7];
    const float* mb  = (const float*)d_in[8];
    const float* rw  = (const float*)d_in[9];
    float* out = (float*)d_out;

    char* ws = (char*)d_ws;
    size_t off = 0;
    auto carve = [&](size_t bytes) -> char* {
        char* p = ws + off;
        off += (bytes + 255) & ~(size_t)255;
        return p;
    };
    unsigned short* hb  = (unsigned short*)carve((size_t)ROWS * CC * 2);   // 25.2 MB
    unsigned short* wbt = (unsigned short*)carve((size_t)NKC * CC * 8 * 2);// 8.25 MB
    unsigned short* wcb = (unsigned short*)carve((size_t)128 * CC * 2);    // 0.20 MB
    float* d    = (float*)carve((size_t)ROWS * 128 * 4);                   // 8.4 MB
    float* gate = (float*)carve((size_t)ROWS * 4);
    int*   i0   = (int*)carve((size_t)NKP * 4);
    int*   i1   = (int*)carve((size_t)NKP * 4);
    float* w0   = (float*)carve((size_t)NKP * 4);
    float* w1   = (float*)carve((size_t)NKP * 4);

    k_ln<<<ROWS, 256, 0, stream>>>(x, am, stm, lnw, lnb, hb, gate);
    k_wbt<<<CC, 256, 0, stream>>>(rw, wbt);
    k_wcb<<<128, 256, 0, stream>>>(ow, mw, wcb);
    k_dg2<<<ROWS / 128, 256, 0, stream>>>(hb, wcb, d);
    k_off<<<NKP / 256, 256, 0, stream>>>(d, ob, mb, gate, i0, i1, w0, w1);
    k_fgemm<<<256, 512, 0, stream>>>(hb, wbt, i0, i1, w0, w1, x, out);
}